// Round 7
// baseline (508.093 us; speedup 1.0000x reference)
//
#include <hip/hip_runtime.h>

// TalkingHeadAttention: B=4, N=1024, C=768, H=12, HD=64
// R6: mixexp2_k occupancy push: 8 keys/thread, VGPR<=128 -> 4 waves/SIMD.
// Post-mortem R5->R6: spill fixed (VGPR 176, logical traffic restored,
// 82us) but VALUBusy 52% @ 2 waves/SIMD (176 VGPR is in the 128<v<=256
// occupancy band). VALU issue time ~43us = the floor; occupancy is the lever.
// This round: sv[12] (48 VGPR, 8 keys/thread) + IN-PLACE overwrite (no
// separate pv array - that's what pushed R3 to 132) + launch_bounds(256,4)
// capping at 128 (live set ~110, safely under - R4's lesson: never cap below
// live set). Row = 2 waves -> small LDS cross-wave sum (R3 pattern).
//   gemm_s16  : batched (b,h) QK^T -> S f16 (computed once)
//   mixexp2_k : S -> att2 = b_w + sum_g softmax(mix1(S))_g w_w[g,g2], in place
//   gemm_pv   : att2 @ V -> x16 (tile 128x64, Bt = Vt planes)
// Fallback: if ws_size < 157.5 MB, run the R1 path (kept verbatim).

#define Bsz   4
#define Nseq  1024
#define Cdim  768
#define Hn    12
#define HDim  64

typedef __attribute__((ext_vector_type(4))) float    f32x4;
typedef __attribute__((ext_vector_type(8))) _Float16 f16x8;
typedef __attribute__((ext_vector_type(4))) _Float16 f16x4;

#define MFMA_F16(A, B, C) __builtin_amdgcn_mfma_f32_16x16x32_f16(A, B, C, 0, 0, 0)

// ---------------- fp32 -> fp16 cast ----------------------------------------
__global__ __launch_bounds__(256) void cvt_f32_f16(
    const float* __restrict__ in, _Float16* __restrict__ out)
{
  const size_t i = (size_t)(blockIdx.x * 256 + threadIdx.x) * 4;
  float4 v = *(const float4*)(in + i);
  f16x4 o;
  o[0] = (_Float16)v.x; o[1] = (_Float16)v.y;
  o[2] = (_Float16)v.z; o[3] = (_Float16)v.w;
  *(f16x4*)(out + i) = o;
}

// ------------- transpose + cast: in[R][C] fp32 -> out[C][R] fp16 -----------
__global__ __launch_bounds__(256) void transpose_cvt(
    const float* __restrict__ in, _Float16* __restrict__ out, int R, int C)
{
  __shared__ float T[64][65];
  const int c0 = blockIdx.x * 64, r0 = blockIdx.y * 64;
  const int lr = threadIdx.x >> 4, lc = (threadIdx.x & 15) * 4;
#pragma unroll
  for (int i = 0; i < 4; ++i) {
    float4 v = *(const float4*)(in + (size_t)(r0 + lr + i*16) * C + c0 + lc);
    T[lr+i*16][lc+0] = v.x; T[lr+i*16][lc+1] = v.y;
    T[lr+i*16][lc+2] = v.z; T[lr+i*16][lc+3] = v.w;
  }
  __syncthreads();
#pragma unroll
  for (int i = 0; i < 4; ++i) {
    const int orow = lr + i*16;
    f16x4 o;
#pragma unroll
    for (int j = 0; j < 4; ++j) o[j] = (_Float16)T[lc+j][orow];
    *(f16x4*)(out + (size_t)(c0 + orow) * R + r0 + lc) = o;
  }
}

// ---------------- fp16 MFMA GEMM, BT form ----------------------------------
__global__ __launch_bounds__(256, 2) void gemm_f16(
    const _Float16* __restrict__ A, const _Float16* __restrict__ Bt,
    const float* __restrict__ bias, _Float16* __restrict__ C16,
    float* __restrict__ C32, int M, int N, int K)
{
  __shared__ _Float16 sA[2][4][512];
  __shared__ _Float16 sB[2][4][512];
  const int tid = threadIdx.x;
  const int w = tid >> 6, lane = tid & 63;
  const int m0 = blockIdx.y * 128, n0 = blockIdx.x * 128;
  const int frow = lane & 15, fk8 = lane >> 4;

  f32x4 acc[4][4];
#pragma unroll
  for (int i = 0; i < 4; ++i)
#pragma unroll
    for (int j = 0; j < 4; ++j) acc[i][j] = (f32x4)0.f;

  const _Float16* gsrc = (w < 2)
      ? A  + (size_t)(m0 + w*64 + frow) * K + fk8 * 8
      : Bt + (size_t)(n0 + (w - 2)*64 + frow) * K + fk8 * 8;

  for (int kt = 0; kt < K; kt += 32) {
    f16x8 st[4];
#pragma unroll
    for (int j = 0; j < 4; ++j)
      st[j] = *(const f16x8*)(gsrc + kt + (size_t)j * 16 * K);
    __syncthreads();
    if (w < 2) {
#pragma unroll
      for (int j = 0; j < 4; ++j) *(f16x8*)&sA[w][j][lane*8] = st[j];
    } else {
#pragma unroll
      for (int j = 0; j < 4; ++j) *(f16x8*)&sB[w-2][j][lane*8] = st[j];
    }
    __syncthreads();
    f16x8 af[4], bf[4];
#pragma unroll
    for (int mi = 0; mi < 4; ++mi) af[mi] = *(const f16x8*)&sA[w & 1][mi][lane*8];
#pragma unroll
    for (int ni = 0; ni < 4; ++ni) bf[ni] = *(const f16x8*)&sB[w >> 1][ni][lane*8];
#pragma unroll
    for (int mi = 0; mi < 4; ++mi)
#pragma unroll
      for (int ni = 0; ni < 4; ++ni)
        acc[mi][ni] = MFMA_F16(af[mi], bf[ni], acc[mi][ni]);
  }

  const int m0w = m0 + (w & 1) * 64, n0w = n0 + (w >> 1) * 64;
#pragma unroll
  for (int mi = 0; mi < 4; ++mi)
#pragma unroll
    for (int ni = 0; ni < 4; ++ni) {
      const int n = n0w + ni*16 + (lane & 15);
#pragma unroll
      for (int r = 0; r < 4; ++r) {
        const int m = m0w + mi*16 + (lane >> 4)*4 + r;
        if (C16) C16[(size_t)m * N + n] = (_Float16)acc[mi][ni][r];
        else     C32[(size_t)m * N + n] = acc[mi][ni][r] + bias[n];
      }
    }
}

// -------- batched QK^T GEMM: S[b][h][q][k] f16, M=N=1024, K=64 -------------
__global__ __launch_bounds__(256, 2) void gemm_s16(
    const _Float16* __restrict__ qkv16, _Float16* __restrict__ S)
{
  __shared__ _Float16 sA[2][4][512];
  __shared__ _Float16 sB[2][4][512];
  const int tid = threadIdx.x;
  const int w = tid >> 6, lane = tid & 63;
  const int m0 = blockIdx.y * 128, n0 = blockIdx.x * 128;
  const int frow = lane & 15, fk8 = lane >> 4;
  const int bh = blockIdx.z;                // 0..47
  const int b = bh / Hn, h = bh % Hn;

  const _Float16* Abase = qkv16 + (size_t)(b * Nseq) * (3*Cdim) + h * HDim;          // Q
  const _Float16* Bbase = Abase + Cdim;                                               // K

  f32x4 acc[4][4];
#pragma unroll
  for (int i = 0; i < 4; ++i)
#pragma unroll
    for (int j = 0; j < 4; ++j) acc[i][j] = (f32x4)0.f;

  const _Float16* gsrc = (w < 2)
      ? Abase + (size_t)(m0 + w*64 + frow) * (3*Cdim) + fk8 * 8
      : Bbase + (size_t)(n0 + (w - 2)*64 + frow) * (3*Cdim) + fk8 * 8;

#pragma unroll
  for (int kt = 0; kt < HDim; kt += 32) {
    f16x8 st[4];
#pragma unroll
    for (int j = 0; j < 4; ++j)
      st[j] = *(const f16x8*)(gsrc + kt + (size_t)j * 16 * (3*Cdim));
    __syncthreads();
    if (w < 2) {
#pragma unroll
      for (int j = 0; j < 4; ++j) *(f16x8*)&sA[w][j][lane*8] = st[j];
    } else {
#pragma unroll
      for (int j = 0; j < 4; ++j) *(f16x8*)&sB[w-2][j][lane*8] = st[j];
    }
    __syncthreads();
    f16x8 af[4], bf[4];
#pragma unroll
    for (int mi = 0; mi < 4; ++mi) af[mi] = *(const f16x8*)&sA[w & 1][mi][lane*8];
#pragma unroll
    for (int ni = 0; ni < 4; ++ni) bf[ni] = *(const f16x8*)&sB[w >> 1][ni][lane*8];
#pragma unroll
    for (int mi = 0; mi < 4; ++mi)
#pragma unroll
      for (int ni = 0; ni < 4; ++ni)
        acc[mi][ni] = MFMA_F16(af[mi], bf[ni], acc[mi][ni]);
  }

  _Float16* out = S + ((size_t)bh << 20);
  const int m0w = m0 + (w & 1) * 64, n0w = n0 + (w >> 1) * 64;
#pragma unroll
  for (int mi = 0; mi < 4; ++mi)
#pragma unroll
    for (int ni = 0; ni < 4; ++ni) {
      const int n = n0w + ni*16 + (lane & 15);
#pragma unroll
      for (int r = 0; r < 4; ++r) {
        const int m = m0w + mi*16 + (lane >> 4)*4 + r;
        out[(size_t)m * Nseq + n] = (_Float16)acc[mi][ni][r];
      }
    }
}

// ------ mix1 + exp + rowsum + normalize + mix2 + b_w, in place -------------
// R6: 8 keys/thread (sv[12]=48 VGPR, in-place overwrite, no pv array),
// launch_bounds(256,4) caps VGPR at 128 (live ~110) -> 4 waves/SIMD.
// Block = 2 q-rows x 1024 keys; row = 2 waves -> LDS cross-wave sum.
// grid = B * N/2 = 2048 blocks. In-place safe: thread-exclusive cells.
__global__ __launch_bounds__(256, 4) void mixexp2_k(
    _Float16* __restrict__ S, const float* __restrict__ w_l,
    const float* __restrict__ w_w, const float* __restrict__ b_w)
{
  __shared__ __attribute__((aligned(16))) float wl_s[144];
  __shared__ __attribute__((aligned(16))) float ww_s[144];
  __shared__ float bw_s[12];
  __shared__ float dred[4][12];
  __shared__ float dfin[2][12];
  const int tid = threadIdx.x;
  if (tid < 144) { wl_s[tid] = w_l[tid] * 0.125f; ww_s[tid] = w_w[tid]; }
  if (tid < 12)  bw_s[tid] = b_w[tid];
  __syncthreads();

  const int b   = blockIdx.x >> 9;
  const int qp  = blockIdx.x & 511;
  const int ql  = tid >> 7;               // 0..1: which q-row of the pair
  const int q   = qp * 2 + ql;
  const int ks  = (tid & 127) * 8;        // 8 keys per thread
  const int w   = tid >> 6;               // wave id (0..3)
  _Float16* base = S + ((size_t)(b*Hn) << 20) + ((size_t)q << 10) + ks;

  // load 12 planes x 8 keys (12 x 16B loads, all independent)
  f16x8 sv[12];
#pragma unroll
  for (int h = 0; h < 12; ++h) sv[h] = *(const f16x8*)(base + ((size_t)h << 20));

  float dacc[12];
#pragma unroll
  for (int g = 0; g < 12; ++g) dacc[g] = 0.f;

  // pass 1: mix1 -> exp; overwrite sv cells with p16
#pragma unroll
  for (int kk = 0; kk < 8; ++kk) {
    float L[12];
#pragma unroll
    for (int g = 0; g < 12; ++g) L[g] = 0.f;
#pragma unroll
    for (int h = 0; h < 12; ++h) {
      const float s = (float)sv[h][kk];
      const f32x4 w0 = *(const f32x4*)&wl_s[h*12];
      const f32x4 w1 = *(const f32x4*)&wl_s[h*12+4];
      const f32x4 w2 = *(const f32x4*)&wl_s[h*12+8];
#pragma unroll
      for (int j = 0; j < 4; ++j) {
        L[j]   = fmaf(s, w0[j], L[j]);
        L[4+j] = fmaf(s, w1[j], L[4+j]);
        L[8+j] = fmaf(s, w2[j], L[8+j]);
      }
    }
#pragma unroll
    for (int g = 0; g < 12; ++g) {
      const _Float16 p16 = (_Float16)__expf(L[g] - 6.0f);
      sv[g][kk] = p16;
      dacc[g] += (float)p16;      // denominator consistent with f16 numerator
    }
  }

  // per-wave reduce over 64 lanes (one wave = half a q-row)
#pragma unroll
  for (int g = 0; g < 12; ++g) {
    float v = dacc[g];
    v += __shfl_xor(v, 1, 64);
    v += __shfl_xor(v, 2, 64);
    v += __shfl_xor(v, 4, 64);
    v += __shfl_xor(v, 8, 64);
    v += __shfl_xor(v, 16, 64);
    v += __shfl_xor(v, 32, 64);
    dacc[g] = v;
  }
  if ((tid & 63) == 0) {
#pragma unroll
    for (int g = 0; g < 12; ++g) dred[w][g] = dacc[g];
  }
  __syncthreads();
  if (tid < 24) {
    const int qi = tid / 12, g = tid % 12;
    dfin[qi][g] = 1.0f / (dred[qi*2][g] + dred[qi*2+1][g]);
  }
  __syncthreads();

  float df[12];
#pragma unroll
  for (int g = 0; g < 12; ++g) df[g] = dfin[ql][g];

  // pass 2: normalize + mix2 (+b_w); overwrite sv with att2
#pragma unroll
  for (int kk = 0; kk < 8; ++kk) {
    float pr[12];
#pragma unroll
    for (int g = 0; g < 12; ++g) pr[g] = (float)sv[g][kk] * df[g];
    float att2[12];
#pragma unroll
    for (int g2 = 0; g2 < 12; ++g2) att2[g2] = bw_s[g2];
#pragma unroll
    for (int g = 0; g < 12; ++g) {
      const f32x4 w0 = *(const f32x4*)&ww_s[g*12];
      const f32x4 w1 = *(const f32x4*)&ww_s[g*12+4];
      const f32x4 w2 = *(const f32x4*)&ww_s[g*12+8];
#pragma unroll
      for (int j = 0; j < 4; ++j) {
        att2[j]   = fmaf(pr[g], w0[j], att2[j]);
        att2[4+j] = fmaf(pr[g], w1[j], att2[4+j]);
        att2[8+j] = fmaf(pr[g], w2[j], att2[8+j]);
      }
    }
#pragma unroll
    for (int g2 = 0; g2 < 12; ++g2) sv[g2][kk] = (_Float16)att2[g2];
  }

  // write att2 planes back (same addresses as read -> in-place safe)
#pragma unroll
  for (int g2 = 0; g2 < 12; ++g2)
    *(f16x8*)(base + ((size_t)g2 << 20)) = sv[g2];
}

// ---------------- prep: V block of qkv16 -> per-head V^T fp16 --------------
__global__ __launch_bounds__(256) void prep_v(
    const _Float16* __restrict__ qkv16, _Float16* __restrict__ Vt)
{
  __shared__ float vt[64][65];
  const int id = blockIdx.x;
  const int nt = id & 15;
  const int h  = (id >> 4) % Hn;
  const int b  = id / (16 * Hn);
  const int n0 = nt * 64;
  const int tid = threadIdx.x;
  const int row = tid >> 2;
  const int c0  = (tid & 3) * 16;

  const _Float16* src = qkv16 + (size_t)(b*Nseq + n0 + row) * (3*Cdim) + 2*Cdim + h*HDim + c0;
  f16x8 v0 = *(const f16x8*)src;
  f16x8 v1 = *(const f16x8*)(src + 8);
#pragma unroll
  for (int j = 0; j < 8; ++j) {
    vt[c0+j][row]   = (float)v0[j];
    vt[c0+8+j][row] = (float)v1[j];
  }
  __syncthreads();
  f16x8 o0, o1;
#pragma unroll
  for (int j = 0; j < 8; ++j) {
    o0[j] = (_Float16)vt[row][c0+j];
    o1[j] = (_Float16)vt[row][c0+8+j];
  }
  _Float16* dst = Vt + (size_t)((b*Hn + h)*HDim + row) * Nseq + n0 + c0;
  *(f16x8*)dst = o0;
  *(f16x8*)(dst + 8) = o1;
}

// -------- PV GEMM: x[b,q,g2*64+d] = att2[b,g2] @ V[b,g2] -------------------
__global__ __launch_bounds__(256, 2) void gemm_pv(
    const _Float16* __restrict__ P, const _Float16* __restrict__ Vt,
    _Float16* __restrict__ x16)
{
  __shared__ _Float16 sA[2][4][512];   // 128 rows x 32 k
  __shared__ _Float16 sB[4][512];      // 64 rows x 32 k
  const int tid = threadIdx.x;
  const int w = tid >> 6, lane = tid & 63;
  const int m0 = blockIdx.y * 128;
  const int bh = blockIdx.z;                 // 0..47
  const int b = bh / Hn, g2 = bh % Hn;
  const int frow = lane & 15, fk8 = lane >> 4;

  const _Float16* Abase = P + ((size_t)bh << 20);
  const _Float16* Bbase = Vt + (size_t)(bh * HDim) * Nseq;

  f32x4 acc[4][2];
#pragma unroll
  for (int i = 0; i < 4; ++i)
#pragma unroll
    for (int j = 0; j < 2; ++j) acc[i][j] = (f32x4)0.f;

  const _Float16* gsrc = (w < 2)
      ? Abase + (size_t)(m0 + w*64 + frow) * Nseq + fk8 * 8
      : Bbase + (size_t)frow * Nseq + fk8 * 8;

  for (int kt = 0; kt < Nseq; kt += 32) {
    f16x8 st[4];
    if (w <= 2) {
#pragma unroll
      for (int j = 0; j < 4; ++j)
        st[j] = *(const f16x8*)(gsrc + kt + (size_t)j * 16 * Nseq);
    }
    __syncthreads();
    if (w < 2) {
#pragma unroll
      for (int j = 0; j < 4; ++j) *(f16x8*)&sA[w][j][lane*8] = st[j];
    } else if (w == 2) {
#pragma unroll
      for (int j = 0; j < 4; ++j) *(f16x8*)&sB[j][lane*8] = st[j];
    }
    __syncthreads();
    f16x8 af[4], bf[2];
#pragma unroll
    for (int mi = 0; mi < 4; ++mi) af[mi] = *(const f16x8*)&sA[w & 1][mi][lane*8];
#pragma unroll
    for (int ni = 0; ni < 2; ++ni) bf[ni] = *(const f16x8*)&sB[(w >> 1)*2 + ni][lane*8];
#pragma unroll
    for (int mi = 0; mi < 4; ++mi)
#pragma unroll
      for (int ni = 0; ni < 2; ++ni)
        acc[mi][ni] = MFMA_F16(af[mi], bf[ni], acc[mi][ni]);
  }

  const int m0w = m0 + (w & 1) * 64, n0w = (w >> 1) * 32;
#pragma unroll
  for (int mi = 0; mi < 4; ++mi)
#pragma unroll
    for (int ni = 0; ni < 2; ++ni) {
      const int n = n0w + ni*16 + (lane & 15);
#pragma unroll
      for (int r = 0; r < 4; ++r) {
        const int m = m0w + mi*16 + (lane >> 4)*4 + r;
        x16[(size_t)(b*Nseq + m) * Cdim + g2*HDim + n] = (_Float16)acc[mi][ni][r];
      }
    }
}

// ======================= fallback path (R1, proven) ========================
__global__ __launch_bounds__(256, 2) void dsum_k(
    const _Float16* __restrict__ qkv16, const float* __restrict__ w_l,
    float* __restrict__ dpart)
{
  __shared__ __attribute__((aligned(16))) float wl_s[144];
  __shared__ float dred[4][16][12];
  const int tid = threadIdx.x;
  const int w = tid >> 6, lane = tid & 63;
  const int col = lane & 15, grp = lane >> 4;
  const int ch = blockIdx.x & 7;
  const int qt = (blockIdx.x >> 3) & 63;
  const int b  = blockIdx.x >> 9;
  const int q0 = qt << 4;

  if (tid < 144) wl_s[tid] = w_l[tid] * 0.125f;

  f16x8 qf[12][2];
  {
    const _Float16* qrow = qkv16 + (size_t)(b*Nseq + q0 + col) * (3*Cdim) + grp*8;
#pragma unroll
    for (int h = 0; h < 12; ++h) {
      qf[h][0] = *(const f16x8*)(qrow + h*HDim);
      qf[h][1] = *(const f16x8*)(qrow + h*HDim + 32);
    }
  }
  __syncthreads();

  float dacc[4][12];
#pragma unroll
  for (int r = 0; r < 4; ++r)
#pragma unroll
    for (int g = 0; g < 12; ++g) dacc[r][g] = 0.f;

#pragma unroll
  for (int kg = 0; kg < 2; ++kg) {
    const int key = ch*128 + kg*64 + w*16 + col;
    const _Float16* krow = qkv16 + (size_t)(b*Nseq + key) * (3*Cdim) + Cdim + grp*8;
    f32x4 S[12];
#pragma unroll
    for (int h = 0; h < 12; ++h) {
      f16x8 b0 = *(const f16x8*)(krow + h*HDim);
      f16x8 b1 = *(const f16x8*)(krow + h*HDim + 32);
      f32x4 s = (f32x4)0.f;
      s = MFMA_F16(qf[h][0], b0, s);
      S[h] = MFMA_F16(qf[h][1], b1, s);
    }
#pragma unroll
    for (int r = 0; r < 4; ++r) {
      float L[12];
#pragma unroll
      for (int g = 0; g < 12; ++g) L[g] = 0.f;
#pragma unroll
      for (int h = 0; h < 12; ++h) {
        const float s = S[h][r];
        const f32x4 w0 = *(const f32x4*)&wl_s[h*12];
        const f32x4 w1 = *(const f32x4*)&wl_s[h*12+4];
        const f32x4 w2 = *(const f32x4*)&wl_s[h*12+8];
#pragma unroll
        for (int j = 0; j < 4; ++j) {
          L[j]   = fmaf(s, w0[j], L[j]);
          L[4+j] = fmaf(s, w1[j], L[4+j]);
          L[8+j] = fmaf(s, w2[j], L[8+j]);
        }
      }
#pragma unroll
      for (int g = 0; g < 12; ++g) dacc[r][g] += __expf(L[g] - 6.0f);
    }
  }
#pragma unroll
  for (int r = 0; r < 4; ++r)
#pragma unroll
    for (int g = 0; g < 12; ++g) {
      float v = dacc[r][g];
      v += __shfl_xor(v, 1, 64);
      v += __shfl_xor(v, 2, 64);
      v += __shfl_xor(v, 4, 64);
      v += __shfl_xor(v, 8, 64);
      dacc[r][g] = v;
    }
  if (col == 0) {
#pragma unroll
    for (int r = 0; r < 4; ++r)
#pragma unroll
      for (int g = 0; g < 12; ++g) dred[w][grp*4+r][g] = dacc[r][g];
  }
  __syncthreads();
  if (tid < 192) {
    const int q = tid / 12, g = tid % 12;
    const float s = dred[0][q][g] + dred[1][q][g] + dred[2][q][g] + dred[3][q][g];
    dpart[((size_t)((b*Hn + g)*Nseq) + q0 + q) * 8 + ch] = s;
  }
}

__global__ __launch_bounds__(256) void dinv_k(
    const float* __restrict__ dpart, float* __restrict__ dinv)
{
  const int i = blockIdx.x * 256 + threadIdx.x;
  const float* p = dpart + (size_t)i * 8;
  f32x4 a = *(const f32x4*)p;
  f32x4 c = *(const f32x4*)(p + 4);
  dinv[i] = 1.0f / (a[0]+a[1]+a[2]+a[3]+c[0]+c[1]+c[2]+c[3]);
}

__global__ __launch_bounds__(256, 2) void pvmix_k(
    const _Float16* __restrict__ qkv16, const _Float16* __restrict__ Vt,
    const float* __restrict__ dinv,
    const float* __restrict__ w_l, const float* __restrict__ w_w,
    const float* __restrict__ b_w, float* __restrict__ x32)
{
  __shared__ _Float16 P_s[12][16][72];
  __shared__ float dinv_s[16][12];
  __shared__ __attribute__((aligned(16))) float wl_s[144];
  __shared__ __attribute__((aligned(16))) float ww_s[144];
  __shared__ float bw_s[12];

  const int tid = threadIdx.x;
  const int w = tid >> 6, lane = tid & 63;
  const int col = lane & 15, grp = lane >> 4;
  const int kh = blockIdx.x & 1;
  const int qt = (blockIdx.x >> 1) & 63;
  const int b  = blockIdx.x >> 7;
  const int q0 = qt << 4;

  if (tid < 144) { wl_s[tid] = w_l[tid] * 0.125f; ww_s[tid] = w_w[tid]; }
  if (tid < 12)  bw_s[tid] = b_w[tid];
  if (tid < 192) {
    const int q = tid / 12, g = tid % 12;
    dinv_s[q][g] = dinv[(size_t)((b*Hn + g)*Nseq) + q0 + q];
  }

  f16x8 qf[12][2];
  {
    const _Float16* qrow = qkv16 + (size_t)(b*Nseq + q0 + col) * (3*Cdim) + grp*8;
#pragma unroll
    for (int h = 0; h < 12; ++h) {
      qf[h][0] = *(const f16x8*)(qrow + h*HDim);
      qf[h][1] = *(const f16x8*)(qrow + h*HDim + 32);
    }
  }
  __syncthreads();

  f32x4 Y[12];
#pragma unroll
  for (int g2 = 0; g2 < 12; ++g2) Y[g2] = (f32x4)0.f;

  for (int c = kh*8; c < kh*8 + 8; ++c) {
    const int k0 = c * 64;
    const _Float16* krow = qkv16 + (size_t)(b*Nseq + k0 + w*16 + col) * (3*Cdim)
                           + Cdim + grp*8;
    f32x4 S[12];
#pragma unroll
    for (int h = 0; h < 12; ++h) {
      f16x8 b0 = *(const f16x8*)(krow + h*HDim);
      f16x8 b1 = *(const f16x8*)(krow + h*HDim + 32);
      f32x4 s = (f32x4)0.f;
      s = MFMA_F16(qf[h][0], b0, s);
      S[h] = MFMA_F16(qf[h][1], b1, s);
    }
    __syncthreads();
#pragma unroll
    for (int r = 0; r < 4; ++r) {
      const int q = grp*4 + r;
      float L[12];
#pragma unroll
      for (int g = 0; g < 12; ++g) L[g] = 0.f;
#pragma unroll
      for (int h = 0; h < 12; ++h) {
        const float s = S[h][r];
        const f32x4 w0 = *(const f32x4*)&wl_s[h*12];
        const f32x4 w1 = *(const f32x4*)&wl_s[h*12+4];
        const f32x4 w2 = *(const f32x4*)&wl_s[h*12+8];
#pragma unroll
        for (int j = 0; j < 4; ++j) {
          L[j]   = fmaf(s, w0[j], L[j]);
          L[4+j] = fmaf(s, w1[j], L[4+j]);
          L[8+j] = fmaf(s, w2[j], L[8+j]);
        }
      }
      float att2[12];
#pragma unroll
      for (int g2 = 0; g2 < 12; ++g2) att2[g2] = bw_s[g2];
#pragma unroll
      for (int g = 0; g < 12; ++g) {
        const float pr = __expf(L[g] - 6.0f) * dinv_s[q][g];
        const f32x4 w0 = *(const f32x4*)&ww_s[g*12];
        const f32x4 w1 = *(const f32x4*)&ww_s[g*12+4];
        const f32x4 w2 = *(const f32x4*)&ww_s[g*12+8];
#pragma unroll
        for (int j = 0; j < 4; ++j) {
          att2[j]   = fmaf(pr, w0[j], att2[j]);
          att2[4+j] = fmaf(pr, w1[j], att2[4+j]);
          att2[8+j] = fmaf(pr, w2[j], att2[8+j]);
        }
      }
#pragma unroll
      for (int g2 = 0; g2 < 12; ++g2)
        P_s[g2][q][w*16 + col] = (_Float16)att2[g2];
    }
    __syncthreads();
#pragma unroll
    for (int g2 = 0; g2 < 12; ++g2) {
      f16x8 a0 = *(const f16x8*)&P_s[g2][col][grp*8];
      f16x8 a1 = *(const f16x8*)&P_s[g2][col][32 + grp*8];
      const _Float16* vb = Vt + (size_t)((b*Hn + g2)*HDim + w*16 + col) * Nseq
                           + k0 + grp*8;
      f16x8 v0 = *(const f16x8*)vb;
      f16x8 v1 = *(const f16x8*)(vb + 32);
      Y[g2] = MFMA_F16(a0, v0, Y[g2]);
      Y[g2] = MFMA_F16(a1, v1, Y[g2]);
    }
  }

#pragma unroll
  for (int g2 = 0; g2 < 12; ++g2)
#pragma unroll
    for (int r = 0; r < 4; ++r)
      atomicAdd(&x32[(size_t)(b*Nseq + q0 + grp*4 + r) * Cdim + g2*HDim + w*16 + col],
                Y[g2][r]);
}

// ===========================================================================
extern "C" void kernel_launch(void* const* d_in, const int* in_sizes, int n_in,
                              void* d_out, int out_size, void* d_ws, size_t ws_size,
                              hipStream_t stream) {
  (void)in_sizes; (void)n_in; (void)out_size;
  const float* inputs = (const float*)d_in[0];
  const float* w_qkv  = (const float*)d_in[1];
  const float* w_l    = (const float*)d_in[2];
  // d_in[3] = b_l: cancels in softmax — unused.
  const float* w_w    = (const float*)d_in[4];
  const float* b_w    = (const float*)d_in[5];
  const float* w_proj = (const float*)d_in[6];
  const float* b_proj = (const float*)d_in[7];
  float* out = (float*)d_out;

  const int M = Bsz * Nseq;  // 4096
  char* ws = (char*)d_ws;
  _Float16* A16   = (_Float16*)ws;                   // 4096x768
  _Float16* BtQKV = A16   + (size_t)M * Cdim;        // 2304x768
  _Float16* BtPrj = BtQKV + (size_t)(3*Cdim) * Cdim; // 768x768
  _Float16* qkv16 = BtPrj + (size_t)Cdim * Cdim;     // 4096x2304
  _Float16* Vt    = qkv16 + (size_t)M * 3 * Cdim;    // (B*H*64)x1024
  _Float16* x16   = Vt    + (size_t)M * Cdim;        // 4096x768
  float*    dpart = (float*)(x16 + (size_t)M * Cdim);        // 49152x8
  float*    dinv  = dpart + (size_t)Bsz*Hn*Nseq*8;           // 49152
  float*    x32   = dinv  + (size_t)Bsz*Hn*Nseq;             // 4096x768
  _Float16* S     = (_Float16*)(x32 + (size_t)M * Cdim);     // 48 x 1024 x 1024

  const size_t NEED = 42467328ull + 14352384ull + 100663296ull;  // 157.5 MB

  cvt_f32_f16<<<dim3((M * Cdim) / 1024), 256, 0, stream>>>(inputs, A16);
  transpose_cvt<<<dim3((3*Cdim)/64, Cdim/64), 256, 0, stream>>>(w_qkv, BtQKV, Cdim, 3*Cdim);
  transpose_cvt<<<dim3(Cdim/64, Cdim/64), 256, 0, stream>>>(w_proj, BtPrj, Cdim, Cdim);

  gemm_f16<<<dim3((3*Cdim)/128, M/128), 256, 0, stream>>>(
      A16, BtQKV, nullptr, qkv16, nullptr, M, 3*Cdim, Cdim);

  prep_v<<<dim3(Bsz*Hn*16), 256, 0, stream>>>(qkv16, Vt);

  if (ws_size >= NEED) {
    // ---- QK GEMM + fused mix/softmax/mix + PV GEMM ----
    gemm_s16<<<dim3(Nseq/128, Nseq/128, Bsz*Hn), 256, 0, stream>>>(qkv16, S);
    mixexp2_k<<<dim3(Bsz*Nseq/2), 256, 0, stream>>>(S, w_l, w_w, b_w);
    gemm_pv<<<dim3(1, Nseq/128, Bsz*Hn), 256, 0, stream>>>(S, Vt, x16);
  } else {
    // ---- fallback: R1 path ----
    dsum_k<<<dim3(Bsz*64*8), 256, 0, stream>>>(qkv16, w_l, dpart);
    dinv_k<<<dim3(Bsz*Hn*Nseq/256), 256, 0, stream>>>(dpart, dinv);
    hipMemsetAsync(x32, 0, (size_t)M*Cdim*sizeof(float), stream);
    pvmix_k<<<dim3(Bsz*64*2), 256, 0, stream>>>(
        qkv16, Vt, dinv, w_l, w_w, b_w, x32);
    cvt_f32_f16<<<dim3((M * Cdim) / 1024), 256, 0, stream>>>(x32, x16);
  }

  gemm_f16<<<dim3(Cdim/128, M/128), 256, 0, stream>>>(
      x16, BtPrj, b_proj, nullptr, out, M, Cdim, Cdim);
}

// Round 8
// 268.831 us; speedup vs baseline: 1.8900x; 1.8900x over previous
//
#include <hip/hip_runtime.h>

// TalkingHeadAttention: B=4, N=1024, C=768, H=12, HD=64
// R7: mixexp2_k launch_bounds (256,4) -> (256,2).
// Post-mortem R6->R7: EMPIRICAL LAW of this toolchain's launch_bounds:
// (256,k) caps VGPR at 256/k [k=2->128 (gemms), k=3->84 (R4 spill),
// k=4->64 (R6 spill; 1.03GB traffic, 325us)]. NOT 512/k as modeled.
// launch_bounds caps ALLOCATION only; runtime residency = 512/VGPR, so
// (256,2) + live set ~110 -> 128 cap, no spill, AND 4 waves/SIMD.
// Structure unchanged from R6: 8 keys/thread (sv[12]=48 VGPR, in-place,
// no pv array), block = 2 q-rows, LDS pair-sum, grid 2048.
//   gemm_s16  : batched (b,h) QK^T -> S f16 (computed once)
//   mixexp2_k : S -> att2 = b_w + sum_g softmax(mix1(S))_g w_w[g,g2], in place
//   gemm_pv   : att2 @ V -> x16 (tile 128x64, Bt = Vt planes)
// Fallback: if ws_size < 157.5 MB, run the R1 path (kept verbatim).

#define Bsz   4
#define Nseq  1024
#define Cdim  768
#define Hn    12
#define HDim  64

typedef __attribute__((ext_vector_type(4))) float    f32x4;
typedef __attribute__((ext_vector_type(8))) _Float16 f16x8;
typedef __attribute__((ext_vector_type(4))) _Float16 f16x4;

#define MFMA_F16(A, B, C) __builtin_amdgcn_mfma_f32_16x16x32_f16(A, B, C, 0, 0, 0)

// ---------------- fp32 -> fp16 cast ----------------------------------------
__global__ __launch_bounds__(256) void cvt_f32_f16(
    const float* __restrict__ in, _Float16* __restrict__ out)
{
  const size_t i = (size_t)(blockIdx.x * 256 + threadIdx.x) * 4;
  float4 v = *(const float4*)(in + i);
  f16x4 o;
  o[0] = (_Float16)v.x; o[1] = (_Float16)v.y;
  o[2] = (_Float16)v.z; o[3] = (_Float16)v.w;
  *(f16x4*)(out + i) = o;
}

// ------------- transpose + cast: in[R][C] fp32 -> out[C][R] fp16 -----------
__global__ __launch_bounds__(256) void transpose_cvt(
    const float* __restrict__ in, _Float16* __restrict__ out, int R, int C)
{
  __shared__ float T[64][65];
  const int c0 = blockIdx.x * 64, r0 = blockIdx.y * 64;
  const int lr = threadIdx.x >> 4, lc = (threadIdx.x & 15) * 4;
#pragma unroll
  for (int i = 0; i < 4; ++i) {
    float4 v = *(const float4*)(in + (size_t)(r0 + lr + i*16) * C + c0 + lc);
    T[lr+i*16][lc+0] = v.x; T[lr+i*16][lc+1] = v.y;
    T[lr+i*16][lc+2] = v.z; T[lr+i*16][lc+3] = v.w;
  }
  __syncthreads();
#pragma unroll
  for (int i = 0; i < 4; ++i) {
    const int orow = lr + i*16;
    f16x4 o;
#pragma unroll
    for (int j = 0; j < 4; ++j) o[j] = (_Float16)T[lc+j][orow];
    *(f16x4*)(out + (size_t)(c0 + orow) * R + r0 + lc) = o;
  }
}

// ---------------- fp16 MFMA GEMM, BT form ----------------------------------
__global__ __launch_bounds__(256, 2) void gemm_f16(
    const _Float16* __restrict__ A, const _Float16* __restrict__ Bt,
    const float* __restrict__ bias, _Float16* __restrict__ C16,
    float* __restrict__ C32, int M, int N, int K)
{
  __shared__ _Float16 sA[2][4][512];
  __shared__ _Float16 sB[2][4][512];
  const int tid = threadIdx.x;
  const int w = tid >> 6, lane = tid & 63;
  const int m0 = blockIdx.y * 128, n0 = blockIdx.x * 128;
  const int frow = lane & 15, fk8 = lane >> 4;

  f32x4 acc[4][4];
#pragma unroll
  for (int i = 0; i < 4; ++i)
#pragma unroll
    for (int j = 0; j < 4; ++j) acc[i][j] = (f32x4)0.f;

  const _Float16* gsrc = (w < 2)
      ? A  + (size_t)(m0 + w*64 + frow) * K + fk8 * 8
      : Bt + (size_t)(n0 + (w - 2)*64 + frow) * K + fk8 * 8;

  for (int kt = 0; kt < K; kt += 32) {
    f16x8 st[4];
#pragma unroll
    for (int j = 0; j < 4; ++j)
      st[j] = *(const f16x8*)(gsrc + kt + (size_t)j * 16 * K);
    __syncthreads();
    if (w < 2) {
#pragma unroll
      for (int j = 0; j < 4; ++j) *(f16x8*)&sA[w][j][lane*8] = st[j];
    } else {
#pragma unroll
      for (int j = 0; j < 4; ++j) *(f16x8*)&sB[w-2][j][lane*8] = st[j];
    }
    __syncthreads();
    f16x8 af[4], bf[4];
#pragma unroll
    for (int mi = 0; mi < 4; ++mi) af[mi] = *(const f16x8*)&sA[w & 1][mi][lane*8];
#pragma unroll
    for (int ni = 0; ni < 4; ++ni) bf[ni] = *(const f16x8*)&sB[w >> 1][ni][lane*8];
#pragma unroll
    for (int mi = 0; mi < 4; ++mi)
#pragma unroll
      for (int ni = 0; ni < 4; ++ni)
        acc[mi][ni] = MFMA_F16(af[mi], bf[ni], acc[mi][ni]);
  }

  const int m0w = m0 + (w & 1) * 64, n0w = n0 + (w >> 1) * 64;
#pragma unroll
  for (int mi = 0; mi < 4; ++mi)
#pragma unroll
    for (int ni = 0; ni < 4; ++ni) {
      const int n = n0w + ni*16 + (lane & 15);
#pragma unroll
      for (int r = 0; r < 4; ++r) {
        const int m = m0w + mi*16 + (lane >> 4)*4 + r;
        if (C16) C16[(size_t)m * N + n] = (_Float16)acc[mi][ni][r];
        else     C32[(size_t)m * N + n] = acc[mi][ni][r] + bias[n];
      }
    }
}

// -------- batched QK^T GEMM: S[b][h][q][k] f16, M=N=1024, K=64 -------------
__global__ __launch_bounds__(256, 2) void gemm_s16(
    const _Float16* __restrict__ qkv16, _Float16* __restrict__ S)
{
  __shared__ _Float16 sA[2][4][512];
  __shared__ _Float16 sB[2][4][512];
  const int tid = threadIdx.x;
  const int w = tid >> 6, lane = tid & 63;
  const int m0 = blockIdx.y * 128, n0 = blockIdx.x * 128;
  const int frow = lane & 15, fk8 = lane >> 4;
  const int bh = blockIdx.z;                // 0..47
  const int b = bh / Hn, h = bh % Hn;

  const _Float16* Abase = qkv16 + (size_t)(b * Nseq) * (3*Cdim) + h * HDim;          // Q
  const _Float16* Bbase = Abase + Cdim;                                               // K

  f32x4 acc[4][4];
#pragma unroll
  for (int i = 0; i < 4; ++i)
#pragma unroll
    for (int j = 0; j < 4; ++j) acc[i][j] = (f32x4)0.f;

  const _Float16* gsrc = (w < 2)
      ? Abase + (size_t)(m0 + w*64 + frow) * (3*Cdim) + fk8 * 8
      : Bbase + (size_t)(n0 + (w - 2)*64 + frow) * (3*Cdim) + fk8 * 8;

#pragma unroll
  for (int kt = 0; kt < HDim; kt += 32) {
    f16x8 st[4];
#pragma unroll
    for (int j = 0; j < 4; ++j)
      st[j] = *(const f16x8*)(gsrc + kt + (size_t)j * 16 * (3*Cdim));
    __syncthreads();
    if (w < 2) {
#pragma unroll
      for (int j = 0; j < 4; ++j) *(f16x8*)&sA[w][j][lane*8] = st[j];
    } else {
#pragma unroll
      for (int j = 0; j < 4; ++j) *(f16x8*)&sB[w-2][j][lane*8] = st[j];
    }
    __syncthreads();
    f16x8 af[4], bf[4];
#pragma unroll
    for (int mi = 0; mi < 4; ++mi) af[mi] = *(const f16x8*)&sA[w & 1][mi][lane*8];
#pragma unroll
    for (int ni = 0; ni < 4; ++ni) bf[ni] = *(const f16x8*)&sB[w >> 1][ni][lane*8];
#pragma unroll
    for (int mi = 0; mi < 4; ++mi)
#pragma unroll
      for (int ni = 0; ni < 4; ++ni)
        acc[mi][ni] = MFMA_F16(af[mi], bf[ni], acc[mi][ni]);
  }

  _Float16* out = S + ((size_t)bh << 20);
  const int m0w = m0 + (w & 1) * 64, n0w = n0 + (w >> 1) * 64;
#pragma unroll
  for (int mi = 0; mi < 4; ++mi)
#pragma unroll
    for (int ni = 0; ni < 4; ++ni) {
      const int n = n0w + ni*16 + (lane & 15);
#pragma unroll
      for (int r = 0; r < 4; ++r) {
        const int m = m0w + mi*16 + (lane >> 4)*4 + r;
        out[(size_t)m * Nseq + n] = (_Float16)acc[mi][ni][r];
      }
    }
}

// ------ mix1 + exp + rowsum + normalize + mix2 + b_w, in place -------------
// 8 keys/thread (sv[12]=48 VGPR, in-place overwrite, no pv array).
// launch_bounds(256,2): cap = 256/2 = 128 >= live ~110 -> no spill; runtime
// residency = 512/VGPR ~= 4 waves/SIMD. Block = 2 q-rows; LDS pair-sum.
// grid = B * N/2 = 2048 blocks. In-place safe: thread-exclusive cells.
__global__ __launch_bounds__(256, 2) void mixexp2_k(
    _Float16* __restrict__ S, const float* __restrict__ w_l,
    const float* __restrict__ w_w, const float* __restrict__ b_w)
{
  __shared__ __attribute__((aligned(16))) float wl_s[144];
  __shared__ __attribute__((aligned(16))) float ww_s[144];
  __shared__ float bw_s[12];
  __shared__ float dred[4][12];
  __shared__ float dfin[2][12];
  const int tid = threadIdx.x;
  if (tid < 144) { wl_s[tid] = w_l[tid] * 0.125f; ww_s[tid] = w_w[tid]; }
  if (tid < 12)  bw_s[tid] = b_w[tid];
  __syncthreads();

  const int b   = blockIdx.x >> 9;
  const int qp  = blockIdx.x & 511;
  const int ql  = tid >> 7;               // 0..1: which q-row of the pair
  const int q   = qp * 2 + ql;
  const int ks  = (tid & 127) * 8;        // 8 keys per thread
  const int w   = tid >> 6;               // wave id (0..3)
  _Float16* base = S + ((size_t)(b*Hn) << 20) + ((size_t)q << 10) + ks;

  // load 12 planes x 8 keys (12 x 16B loads, all independent)
  f16x8 sv[12];
#pragma unroll
  for (int h = 0; h < 12; ++h) sv[h] = *(const f16x8*)(base + ((size_t)h << 20));

  float dacc[12];
#pragma unroll
  for (int g = 0; g < 12; ++g) dacc[g] = 0.f;

  // pass 1: mix1 -> exp; overwrite sv cells with p16
#pragma unroll
  for (int kk = 0; kk < 8; ++kk) {
    float L[12];
#pragma unroll
    for (int g = 0; g < 12; ++g) L[g] = 0.f;
#pragma unroll
    for (int h = 0; h < 12; ++h) {
      const float s = (float)sv[h][kk];
      const f32x4 w0 = *(const f32x4*)&wl_s[h*12];
      const f32x4 w1 = *(const f32x4*)&wl_s[h*12+4];
      const f32x4 w2 = *(const f32x4*)&wl_s[h*12+8];
#pragma unroll
      for (int j = 0; j < 4; ++j) {
        L[j]   = fmaf(s, w0[j], L[j]);
        L[4+j] = fmaf(s, w1[j], L[4+j]);
        L[8+j] = fmaf(s, w2[j], L[8+j]);
      }
    }
#pragma unroll
    for (int g = 0; g < 12; ++g) {
      const _Float16 p16 = (_Float16)__expf(L[g] - 6.0f);
      sv[g][kk] = p16;
      dacc[g] += (float)p16;      // denominator consistent with f16 numerator
    }
  }

  // per-wave reduce over 64 lanes (one wave = half a q-row)
#pragma unroll
  for (int g = 0; g < 12; ++g) {
    float v = dacc[g];
    v += __shfl_xor(v, 1, 64);
    v += __shfl_xor(v, 2, 64);
    v += __shfl_xor(v, 4, 64);
    v += __shfl_xor(v, 8, 64);
    v += __shfl_xor(v, 16, 64);
    v += __shfl_xor(v, 32, 64);
    dacc[g] = v;
  }
  if ((tid & 63) == 0) {
#pragma unroll
    for (int g = 0; g < 12; ++g) dred[w][g] = dacc[g];
  }
  __syncthreads();
  if (tid < 24) {
    const int qi = tid / 12, g = tid % 12;
    dfin[qi][g] = 1.0f / (dred[qi*2][g] + dred[qi*2+1][g]);
  }
  __syncthreads();

  float df[12];
#pragma unroll
  for (int g = 0; g < 12; ++g) df[g] = dfin[ql][g];

  // pass 2: normalize + mix2 (+b_w); overwrite sv with att2
#pragma unroll
  for (int kk = 0; kk < 8; ++kk) {
    float pr[12];
#pragma unroll
    for (int g = 0; g < 12; ++g) pr[g] = (float)sv[g][kk] * df[g];
    float att2[12];
#pragma unroll
    for (int g2 = 0; g2 < 12; ++g2) att2[g2] = bw_s[g2];
#pragma unroll
    for (int g = 0; g < 12; ++g) {
      const f32x4 w0 = *(const f32x4*)&ww_s[g*12];
      const f32x4 w1 = *(const f32x4*)&ww_s[g*12+4];
      const f32x4 w2 = *(const f32x4*)&ww_s[g*12+8];
#pragma unroll
      for (int j = 0; j < 4; ++j) {
        att2[j]   = fmaf(pr[g], w0[j], att2[j]);
        att2[4+j] = fmaf(pr[g], w1[j], att2[4+j]);
        att2[8+j] = fmaf(pr[g], w2[j], att2[8+j]);
      }
    }
#pragma unroll
    for (int g2 = 0; g2 < 12; ++g2) sv[g2][kk] = (_Float16)att2[g2];
  }

  // write att2 planes back (same addresses as read -> in-place safe)
#pragma unroll
  for (int g2 = 0; g2 < 12; ++g2)
    *(f16x8*)(base + ((size_t)g2 << 20)) = sv[g2];
}

// ---------------- prep: V block of qkv16 -> per-head V^T fp16 --------------
__global__ __launch_bounds__(256) void prep_v(
    const _Float16* __restrict__ qkv16, _Float16* __restrict__ Vt)
{
  __shared__ float vt[64][65];
  const int id = blockIdx.x;
  const int nt = id & 15;
  const int h  = (id >> 4) % Hn;
  const int b  = id / (16 * Hn);
  const int n0 = nt * 64;
  const int tid = threadIdx.x;
  const int row = tid >> 2;
  const int c0  = (tid & 3) * 16;

  const _Float16* src = qkv16 + (size_t)(b*Nseq + n0 + row) * (3*Cdim) + 2*Cdim + h*HDim + c0;
  f16x8 v0 = *(const f16x8*)src;
  f16x8 v1 = *(const f16x8*)(src + 8);
#pragma unroll
  for (int j = 0; j < 8; ++j) {
    vt[c0+j][row]   = (float)v0[j];
    vt[c0+8+j][row] = (float)v1[j];
  }
  __syncthreads();
  f16x8 o0, o1;
#pragma unroll
  for (int j = 0; j < 8; ++j) {
    o0[j] = (_Float16)vt[row][c0+j];
    o1[j] = (_Float16)vt[row][c0+8+j];
  }
  _Float16* dst = Vt + (size_t)((b*Hn + h)*HDim + row) * Nseq + n0 + c0;
  *(f16x8*)dst = o0;
  *(f16x8*)(dst + 8) = o1;
}

// -------- PV GEMM: x[b,q,g2*64+d] = att2[b,g2] @ V[b,g2] -------------------
__global__ __launch_bounds__(256, 2) void gemm_pv(
    const _Float16* __restrict__ P, const _Float16* __restrict__ Vt,
    _Float16* __restrict__ x16)
{
  __shared__ _Float16 sA[2][4][512];   // 128 rows x 32 k
  __shared__ _Float16 sB[4][512];      // 64 rows x 32 k
  const int tid = threadIdx.x;
  const int w = tid >> 6, lane = tid & 63;
  const int m0 = blockIdx.y * 128;
  const int bh = blockIdx.z;                 // 0..47
  const int b = bh / Hn, g2 = bh % Hn;
  const int frow = lane & 15, fk8 = lane >> 4;

  const _Float16* Abase = P + ((size_t)bh << 20);
  const _Float16* Bbase = Vt + (size_t)(bh * HDim) * Nseq;

  f32x4 acc[4][2];
#pragma unroll
  for (int i = 0; i < 4; ++i)
#pragma unroll
    for (int j = 0; j < 2; ++j) acc[i][j] = (f32x4)0.f;

  const _Float16* gsrc = (w < 2)
      ? Abase + (size_t)(m0 + w*64 + frow) * Nseq + fk8 * 8
      : Bbase + (size_t)frow * Nseq + fk8 * 8;

  for (int kt = 0; kt < Nseq; kt += 32) {
    f16x8 st[4];
    if (w <= 2) {
#pragma unroll
      for (int j = 0; j < 4; ++j)
        st[j] = *(const f16x8*)(gsrc + kt + (size_t)j * 16 * Nseq);
    }
    __syncthreads();
    if (w < 2) {
#pragma unroll
      for (int j = 0; j < 4; ++j) *(f16x8*)&sA[w][j][lane*8] = st[j];
    } else if (w == 2) {
#pragma unroll
      for (int j = 0; j < 4; ++j) *(f16x8*)&sB[j][lane*8] = st[j];
    }
    __syncthreads();
    f16x8 af[4], bf[2];
#pragma unroll
    for (int mi = 0; mi < 4; ++mi) af[mi] = *(const f16x8*)&sA[w & 1][mi][lane*8];
#pragma unroll
    for (int ni = 0; ni < 2; ++ni) bf[ni] = *(const f16x8*)&sB[(w >> 1)*2 + ni][lane*8];
#pragma unroll
    for (int mi = 0; mi < 4; ++mi)
#pragma unroll
      for (int ni = 0; ni < 2; ++ni)
        acc[mi][ni] = MFMA_F16(af[mi], bf[ni], acc[mi][ni]);
  }

  const int m0w = m0 + (w & 1) * 64, n0w = (w >> 1) * 32;
#pragma unroll
  for (int mi = 0; mi < 4; ++mi)
#pragma unroll
    for (int ni = 0; ni < 2; ++ni) {
      const int n = n0w + ni*16 + (lane & 15);
#pragma unroll
      for (int r = 0; r < 4; ++r) {
        const int m = m0w + mi*16 + (lane >> 4)*4 + r;
        x16[(size_t)(b*Nseq + m) * Cdim + g2*HDim + n] = (_Float16)acc[mi][ni][r];
      }
    }
}

// ======================= fallback path (R1, proven) ========================
__global__ __launch_bounds__(256, 2) void dsum_k(
    const _Float16* __restrict__ qkv16, const float* __restrict__ w_l,
    float* __restrict__ dpart)
{
  __shared__ __attribute__((aligned(16))) float wl_s[144];
  __shared__ float dred[4][16][12];
  const int tid = threadIdx.x;
  const int w = tid >> 6, lane = tid & 63;
  const int col = lane & 15, grp = lane >> 4;
  const int ch = blockIdx.x & 7;
  const int qt = (blockIdx.x >> 3) & 63;
  const int b  = blockIdx.x >> 9;
  const int q0 = qt << 4;

  if (tid < 144) wl_s[tid] = w_l[tid] * 0.125f;

  f16x8 qf[12][2];
  {
    const _Float16* qrow = qkv16 + (size_t)(b*Nseq + q0 + col) * (3*Cdim) + grp*8;
#pragma unroll
    for (int h = 0; h < 12; ++h) {
      qf[h][0] = *(const f16x8*)(qrow + h*HDim);
      qf[h][1] = *(const f16x8*)(qrow + h*HDim + 32);
    }
  }
  __syncthreads();

  float dacc[4][12];
#pragma unroll
  for (int r = 0; r < 4; ++r)
#pragma unroll
    for (int g = 0; g < 12; ++g) dacc[r][g] = 0.f;

#pragma unroll
  for (int kg = 0; kg < 2; ++kg) {
    const int key = ch*128 + kg*64 + w*16 + col;
    const _Float16* krow = qkv16 + (size_t)(b*Nseq + key) * (3*Cdim) + Cdim + grp*8;
    f32x4 S[12];
#pragma unroll
    for (int h = 0; h < 12; ++h) {
      f16x8 b0 = *(const f16x8*)(krow + h*HDim);
      f16x8 b1 = *(const f16x8*)(krow + h*HDim + 32);
      f32x4 s = (f32x4)0.f;
      s = MFMA_F16(qf[h][0], b0, s);
      S[h] = MFMA_F16(qf[h][1], b1, s);
    }
#pragma unroll
    for (int r = 0; r < 4; ++r) {
      float L[12];
#pragma unroll
      for (int g = 0; g < 12; ++g) L[g] = 0.f;
#pragma unroll
      for (int h = 0; h < 12; ++h) {
        const float s = S[h][r];
        const f32x4 w0 = *(const f32x4*)&wl_s[h*12];
        const f32x4 w1 = *(const f32x4*)&wl_s[h*12+4];
        const f32x4 w2 = *(const f32x4*)&wl_s[h*12+8];
#pragma unroll
        for (int j = 0; j < 4; ++j) {
          L[j]   = fmaf(s, w0[j], L[j]);
          L[4+j] = fmaf(s, w1[j], L[4+j]);
          L[8+j] = fmaf(s, w2[j], L[8+j]);
        }
      }
#pragma unroll
      for (int g = 0; g < 12; ++g) dacc[r][g] += __expf(L[g] - 6.0f);
    }
  }
#pragma unroll
  for (int r = 0; r < 4; ++r)
#pragma unroll
    for (int g = 0; g < 12; ++g) {
      float v = dacc[r][g];
      v += __shfl_xor(v, 1, 64);
      v += __shfl_xor(v, 2, 64);
      v += __shfl_xor(v, 4, 64);
      v += __shfl_xor(v, 8, 64);
      dacc[r][g] = v;
    }
  if (col == 0) {
#pragma unroll
    for (int r = 0; r < 4; ++r)
#pragma unroll
      for (int g = 0; g < 12; ++g) dred[w][grp*4+r][g] = dacc[r][g];
  }
  __syncthreads();
  if (tid < 192) {
    const int q = tid / 12, g = tid % 12;
    const float s = dred[0][q][g] + dred[1][q][g] + dred[2][q][g] + dred[3][q][g];
    dpart[((size_t)((b*Hn + g)*Nseq) + q0 + q) * 8 + ch] = s;
  }
}

__global__ __launch_bounds__(256) void dinv_k(
    const float* __restrict__ dpart, float* __restrict__ dinv)
{
  const int i = blockIdx.x * 256 + threadIdx.x;
  const float* p = dpart + (size_t)i * 8;
  f32x4 a = *(const f32x4*)p;
  f32x4 c = *(const f32x4*)(p + 4);
  dinv[i] = 1.0f / (a[0]+a[1]+a[2]+a[3]+c[0]+c[1]+c[2]+c[3]);
}

__global__ __launch_bounds__(256, 2) void pvmix_k(
    const _Float16* __restrict__ qkv16, const _Float16* __restrict__ Vt,
    const float* __restrict__ dinv,
    const float* __restrict__ w_l, const float* __restrict__ w_w,
    const float* __restrict__ b_w, float* __restrict__ x32)
{
  __shared__ _Float16 P_s[12][16][72];
  __shared__ float dinv_s[16][12];
  __shared__ __attribute__((aligned(16))) float wl_s[144];
  __shared__ __attribute__((aligned(16))) float ww_s[144];
  __shared__ float bw_s[12];

  const int tid = threadIdx.x;
  const int w = tid >> 6, lane = tid & 63;
  const int col = lane & 15, grp = lane >> 4;
  const int kh = blockIdx.x & 1;
  const int qt = (blockIdx.x >> 1) & 63;
  const int b  = blockIdx.x >> 7;
  const int q0 = qt << 4;

  if (tid < 144) { wl_s[tid] = w_l[tid] * 0.125f; ww_s[tid] = w_w[tid]; }
  if (tid < 12)  bw_s[tid] = b_w[tid];
  if (tid < 192) {
    const int q = tid / 12, g = tid % 12;
    dinv_s[q][g] = dinv[(size_t)((b*Hn + g)*Nseq) + q0 + q];
  }

  f16x8 qf[12][2];
  {
    const _Float16* qrow = qkv16 + (size_t)(b*Nseq + q0 + col) * (3*Cdim) + grp*8;
#pragma unroll
    for (int h = 0; h < 12; ++h) {
      qf[h][0] = *(const f16x8*)(qrow + h*HDim);
      qf[h][1] = *(const f16x8*)(qrow + h*HDim + 32);
    }
  }
  __syncthreads();

  f32x4 Y[12];
#pragma unroll
  for (int g2 = 0; g2 < 12; ++g2) Y[g2] = (f32x4)0.f;

  for (int c = kh*8; c < kh*8 + 8; ++c) {
    const int k0 = c * 64;
    const _Float16* krow = qkv16 + (size_t)(b*Nseq + k0 + w*16 + col) * (3*Cdim)
                           + Cdim + grp*8;
    f32x4 S[12];
#pragma unroll
    for (int h = 0; h < 12; ++h) {
      f16x8 b0 = *(const f16x8*)(krow + h*HDim);
      f16x8 b1 = *(const f16x8*)(krow + h*HDim + 32);
      f32x4 s = (f32x4)0.f;
      s = MFMA_F16(qf[h][0], b0, s);
      S[h] = MFMA_F16(qf[h][1], b1, s);
    }
    __syncthreads();
#pragma unroll
    for (int r = 0; r < 4; ++r) {
      const int q = grp*4 + r;
      float L[12];
#pragma unroll
      for (int g = 0; g < 12; ++g) L[g] = 0.f;
#pragma unroll
      for (int h = 0; h < 12; ++h) {
        const float s = S[h][r];
        const f32x4 w0 = *(const f32x4*)&wl_s[h*12];
        const f32x4 w1 = *(const f32x4*)&wl_s[h*12+4];
        const f32x4 w2 = *(const f32x4*)&wl_s[h*12+8];
#pragma unroll
        for (int j = 0; j < 4; ++j) {
          L[j]   = fmaf(s, w0[j], L[j]);
          L[4+j] = fmaf(s, w1[j], L[4+j]);
          L[8+j] = fmaf(s, w2[j], L[8+j]);
        }
      }
      float att2[12];
#pragma unroll
      for (int g2 = 0; g2 < 12; ++g2) att2[g2] = bw_s[g2];
#pragma unroll
      for (int g = 0; g < 12; ++g) {
        const float pr = __expf(L[g] - 6.0f) * dinv_s[q][g];
        const f32x4 w0 = *(const f32x4*)&ww_s[g*12];
        const f32x4 w1 = *(const f32x4*)&ww_s[g*12+4];
        const f32x4 w2 = *(const f32x4*)&ww_s[g*12+8];
#pragma unroll
        for (int j = 0; j < 4; ++j) {
          att2[j]   = fmaf(pr, w0[j], att2[j]);
          att2[4+j] = fmaf(pr, w1[j], att2[4+j]);
          att2[8+j] = fmaf(pr, w2[j], att2[8+j]);
        }
      }
#pragma unroll
      for (int g2 = 0; g2 < 12; ++g2)
        P_s[g2][q][w*16 + col] = (_Float16)att2[g2];
    }
    __syncthreads();
#pragma unroll
    for (int g2 = 0; g2 < 12; ++g2) {
      f16x8 a0 = *(const f16x8*)&P_s[g2][col][grp*8];
      f16x8 a1 = *(const f16x8*)&P_s[g2][col][32 + grp*8];
      const _Float16* vb = Vt + (size_t)((b*Hn + g2)*HDim + w*16 + col) * Nseq
                           + k0 + grp*8;
      f16x8 v0 = *(const f16x8*)vb;
      f16x8 v1 = *(const f16x8*)(vb + 32);
      Y[g2] = MFMA_F16(a0, v0, Y[g2]);
      Y[g2] = MFMA_F16(a1, v1, Y[g2]);
    }
  }

#pragma unroll
  for (int g2 = 0; g2 < 12; ++g2)
#pragma unroll
    for (int r = 0; r < 4; ++r)
      atomicAdd(&x32[(size_t)(b*Nseq + q0 + grp*4 + r) * Cdim + g2*HDim + w*16 + col],
                Y[g2][r]);
}

// ===========================================================================
extern "C" void kernel_launch(void* const* d_in, const int* in_sizes, int n_in,
                              void* d_out, int out_size, void* d_ws, size_t ws_size,
                              hipStream_t stream) {
  (void)in_sizes; (void)n_in; (void)out_size;
  const float* inputs = (const float*)d_in[0];
  const float* w_qkv  = (const float*)d_in[1];
  const float* w_l    = (const float*)d_in[2];
  // d_in[3] = b_l: cancels in softmax — unused.
  const float* w_w    = (const float*)d_in[4];
  const float* b_w    = (const float*)d_in[5];
  const float* w_proj = (const float*)d_in[6];
  const float* b_proj = (const float*)d_in[7];
  float* out = (float*)d_out;

  const int M = Bsz * Nseq;  // 4096
  char* ws = (char*)d_ws;
  _Float16* A16   = (_Float16*)ws;                   // 4096x768
  _Float16* BtQKV = A16   + (size_t)M * Cdim;        // 2304x768
  _Float16* BtPrj = BtQKV + (size_t)(3*Cdim) * Cdim; // 768x768
  _Float16* qkv16 = BtPrj + (size_t)Cdim * Cdim;     // 4096x2304
  _Float16* Vt    = qkv16 + (size_t)M * 3 * Cdim;    // (B*H*64)x1024
  _Float16* x16   = Vt    + (size_t)M * Cdim;        // 4096x768
  float*    dpart = (float*)(x16 + (size_t)M * Cdim);        // 49152x8
  float*    dinv  = dpart + (size_t)Bsz*Hn*Nseq*8;           // 49152
  float*    x32   = dinv  + (size_t)Bsz*Hn*Nseq;             // 4096x768
  _Float16* S     = (_Float16*)(x32 + (size_t)M * Cdim);     // 48 x 1024 x 1024

  const size_t NEED = 42467328ull + 14352384ull + 100663296ull;  // 157.5 MB

  cvt_f32_f16<<<dim3((M * Cdim) / 1024), 256, 0, stream>>>(inputs, A16);
  transpose_cvt<<<dim3((3*Cdim)/64, Cdim/64), 256, 0, stream>>>(w_qkv, BtQKV, Cdim, 3*Cdim);
  transpose_cvt<<<dim3(Cdim/64, Cdim/64), 256, 0, stream>>>(w_proj, BtPrj, Cdim, Cdim);

  gemm_f16<<<dim3((3*Cdim)/128, M/128), 256, 0, stream>>>(
      A16, BtQKV, nullptr, qkv16, nullptr, M, 3*Cdim, Cdim);

  prep_v<<<dim3(Bsz*Hn*16), 256, 0, stream>>>(qkv16, Vt);

  if (ws_size >= NEED) {
    // ---- QK GEMM + fused mix/softmax/mix + PV GEMM ----
    gemm_s16<<<dim3(Nseq/128, Nseq/128, Bsz*Hn), 256, 0, stream>>>(qkv16, S);
    mixexp2_k<<<dim3(Bsz*Nseq/2), 256, 0, stream>>>(S, w_l, w_w, b_w);
    gemm_pv<<<dim3(1, Nseq/128, Bsz*Hn), 256, 0, stream>>>(S, Vt, x16);
  } else {
    // ---- fallback: R1 path ----
    dsum_k<<<dim3(Bsz*64*8), 256, 0, stream>>>(qkv16, w_l, dpart);
    dinv_k<<<dim3(Bsz*Hn*Nseq/256), 256, 0, stream>>>(dpart, dinv);
    hipMemsetAsync(x32, 0, (size_t)M*Cdim*sizeof(float), stream);
    pvmix_k<<<dim3(Bsz*64*2), 256, 0, stream>>>(
        qkv16, Vt, dinv, w_l, w_w, b_w, x32);
    cvt_f32_f16<<<dim3((M * Cdim) / 1024), 256, 0, stream>>>(x32, x16);
  }

  gemm_f16<<<dim3(Cdim/128, M/128), 256, 0, stream>>>(
      x16, BtPrj, b_proj, nullptr, out, M, Cdim, Cdim);
}